// Round 8
// baseline (504.861 us; speedup 1.0000x reference)
//
#include <hip/hip_runtime.h>
#include <stdint.h>

// DCNv2 x3 for MI355X. fp32 I/O, fp16 internal + MFMA f16.
// R8 = R7 with k_gmain staging widened to BK=64 (2 K-steps per barrier):
//      halves barrier count, doubles prefetch cover before the vmcnt(0) drain.
//      goffs/prep/reduces unchanged (R6/R7-proven).

#define HH 96
#define WW 96
#define BBATCH 4
#define HWP (HH*WW)        // 9216
#define PTOT (BBATCH*HWP)  // 36864

typedef _Float16 f16x8 __attribute__((ext_vector_type(8)));
typedef _Float16 h2    __attribute__((ext_vector_type(2)));
typedef float f32x4 __attribute__((ext_vector_type(4)));

union U16x8 { uint4 q; _Float16 h[8]; h2 v[4]; };
union UB    { uint4 q; f16x8 f; };
union UH4   { uint2 d; _Float16 h[4]; };

// ---- NCHW(f32, C=64) -> NHWC(f16) ----
__global__ void k_nchw2nhwc(const float* __restrict__ in, _Float16* __restrict__ out){
  __shared__ float t[32][33];
  int b = blockIdx.z;
  int p0 = blockIdx.x*32, c0 = blockIdx.y*32;
  int tx = threadIdx.x, ty = threadIdx.y; // 32x8
  #pragma unroll
  for(int i=0;i<32;i+=8)
    t[ty+i][tx] = in[((size_t)(b*64 + c0+ty+i))*HWP + p0+tx];
  __syncthreads();
  #pragma unroll
  for(int i=0;i<32;i+=8)
    out[((size_t)(b*HWP + p0+ty+i))*64 + c0+tx] = (_Float16)t[tx][ty+i];
}

// ---- ow [27][CIN][3][3] f32 -> owT [9][32][CIN] f16, rows 27..31 zero ----
template<int CIN>
__global__ void k_tow(const float* __restrict__ ow, _Float16* __restrict__ owT){
  int i = blockIdx.x*256 + threadIdx.x;
  if(i >= 9*32*CIN) return;
  int c = i % CIN; int j = (i/CIN)&31; int k = i/(CIN*32);
  owT[i] = (j<27) ? (_Float16)ow[((size_t)(j*CIN + c))*9 + k] : (_Float16)0.f;
}

// ---- w [COUT][CIN][3][3] f32 -> wT [9][COUT][CIN] f16 ----
template<int CIN,int COUT>
__global__ void k_tw(const float* __restrict__ w, _Float16* __restrict__ wT){
  int i = blockIdx.x*256 + threadIdx.x;
  if(i >= 9*COUT*CIN) return;
  int c = i % CIN; int o = (i/CIN)%COUT; int k = i/(CIN*COUT);
  wT[i] = (_Float16)w[((size_t)(o*CIN + c))*9 + k];
}

// ---- offset conv GEMM, NT taps per block (R6 verbatim) ----
template<int CIN,int NT>
__launch_bounds__(256,2)
__global__ void k_goffs(const _Float16* __restrict__ xin, const _Float16* __restrict__ owT,
                        float* __restrict__ om){
  __shared__ __align__(16) _Float16 As[64*40];
  __shared__ __align__(16) _Float16 Bs[32*40];
  int pos0 = blockIdx.x*64;
  int K0 = blockIdx.y*NT;
  float* omo = om + (size_t)blockIdx.y*PTOT*32;
  int t = threadIdx.x;
  int lane = t&63, wave = t>>6;
  int quad = lane>>4, l15 = lane&15;
  f32x4 acc[2] = {};
  int pa = t>>2, ca = (t&3)*8;
  int P = pos0 + pa;
  int b = P/HWP, rem = P%HWP;
  int y = rem/WW, x = rem%WW;
  #pragma unroll 1
  for(int k=K0;k<K0+NT;k++){
    int iy = y + k/3 - 1, ix = x + k%3 - 1;
    bool valid = (iy>=0)&&(iy<HH)&&(ix>=0)&&(ix<WW);
    const _Float16* src = xin + (((size_t)b*HWP + iy*WW + ix)*CIN) + ca;
    #pragma unroll 1
    for(int c0=0;c0<CIN;c0+=32){
      uint4 av = make_uint4(0,0,0,0);
      if(valid) av = *(const uint4*)(src + c0);
      *(uint4*)&As[pa*40 + ca] = av;
      if(t < 128){
        int j = t>>2;
        *(uint4*)&Bs[j*40 + ca] = *(const uint4*)(owT + ((size_t)k*32 + j)*CIN + c0 + ca);
      }
      __syncthreads();
      UB afu; afu.q = *(const uint4*)&As[(wave*16 + l15)*40 + quad*8];
      #pragma unroll
      for(int ni=0;ni<2;ni++){
        UB bu; bu.q = *(const uint4*)&Bs[(ni*16 + l15)*40 + quad*8];
        acc[ni] = __builtin_amdgcn_mfma_f32_16x16x32_f16(afu.f, bu.f, acc[ni], 0,0,0);
      }
      __syncthreads();
    }
  }
  #pragma unroll
  for(int ni=0;ni<2;ni++)
    #pragma unroll
    for(int r=0;r<4;r++){
      int row = wave*16 + quad*4 + r;
      omo[(size_t)(pos0+row)*32 + ni*16 + l15] = acc[ni][r];
    }
}

// ---- per-(p,k) sampling params; sums NS om slabs (R6 verbatim) ----
template<int NS>
__global__ void k_prep(const float* __restrict__ om, const float* __restrict__ ob,
                       float* __restrict__ pym){
  int i = blockIdx.x*256 + threadIdx.x;
  if(i >= PTOT*9) return;
  int k = i%9, p = i/9;
  int rem = p%HWP;
  int y = rem/WW, x = rem%WW;
  float oy=0.f, ox=0.f, mm=0.f;
  #pragma unroll
  for(int s=0;s<NS;s++){
    const float* o = om + (size_t)s*PTOT*32 + (size_t)p*32;
    oy += o[2*k]; ox += o[2*k+1]; mm += o[18+k];
  }
  oy += ob[2*k]; ox += ob[2*k+1]; mm += ob[18+k];
  float m = 1.f/(1.f + expf(-mm));
  pym[(size_t)i*3+0] = (float)(y + k/3 - 1) + oy;
  pym[(size_t)i*3+1] = (float)(x + k%3 - 1) + ox;
  pym[(size_t)i*3+2] = m;
}

// ---- main DCN GEMM, R8: BK=64 staging, dbuf As, 1 barrier/staging.
//      MODE 0: 9 taps, f16 NHWC out (+bias).
//      MODE 1: 3 taps (blockIdx.z), fp32 partial out (no bias).
template<int CIN,int COUT,int BN,int MODE>
__launch_bounds__(256,2)
__global__ void k_gmain(const _Float16* __restrict__ xin, const float* __restrict__ pym,
                        const _Float16* __restrict__ wT, const float* __restrict__ bias,
                        void* __restrict__ outv){
  constexpr int NW = BN/4;      // per-wave N width
  constexpr int NF = NW/16;     // n-frags per wave
  __shared__ __align__(16) _Float16 As[2][64*72];   // 64 pos x 64ch, stride 72
  int bx = blockIdx.x;
  int lin = (bx>>3) + (bx&7)*(gridDim.x>>3);   // bijective: gridDim.x % 8 == 0
  int pos0 = lin*64;
  int o0 = blockIdx.y*BN;
  int K0 = (MODE==1) ? blockIdx.z*3 : 0;
  constexpr int KN = (MODE==1) ? 3 : 9;
  int t = threadIdx.x;
  int lane = t&63, wave = t>>6;
  int quad = lane>>4, l15 = lane&15;
  f32x4 acc[4][NF] = {};
  int pa = t>>2, ca = (t&3)*16;   // 16 channels per thread
  int P = pos0 + pa;
  int b = P/HWP;
  const _Float16* base = xin + (size_t)b*HWP*CIN + ca;
  const _Float16* wbase = wT + ((size_t)(o0 + wave*NW + l15))*CIN + quad*8;
  int buf = 0;
  #pragma unroll 1
  for(int k=K0;k<K0+KN;k++){
    const float* pp = pym + ((size_t)P*9 + k)*3;
    float py = pp[0], px = pp[1], mk = pp[2];
    float y0f = floorf(py), x0f = floorf(px);
    float wy = py - y0f, wx = px - x0f;
    int iy0 = (int)y0f, ix0 = (int)x0f;
    int iy1 = iy0+1, ix1 = ix0+1;
    bool vy0 = (iy0>=0)&&(iy0<HH), vy1 = (iy1>=0)&&(iy1<HH);
    bool vx0 = (ix0>=0)&&(ix0<WW), vx1 = (ix1>=0)&&(ix1<WW);
    float w00 = (vy0&&vx0) ? (1.f-wy)*(1.f-wx)*mk : 0.f;
    float w01 = (vy0&&vx1) ? (1.f-wy)*wx*mk      : 0.f;
    float w10 = (vy1&&vx0) ? wy*(1.f-wx)*mk      : 0.f;
    float w11 = (vy1&&vx1) ? wy*wx*mk            : 0.f;
    int cy0 = min(max(iy0,0),HH-1), cy1 = min(max(iy1,0),HH-1);
    int cx0 = min(max(ix0,0),WW-1), cx1 = min(max(ix1,0),WW-1);
    const _Float16* pc[4];
    pc[0] = base + ((size_t)(cy0*WW+cx0))*CIN;
    pc[1] = base + ((size_t)(cy0*WW+cx1))*CIN;
    pc[2] = base + ((size_t)(cy1*WW+cx0))*CIN;
    pc[3] = base + ((size_t)(cy1*WW+cx1))*CIN;
    const _Float16* wk = wbase + (size_t)k*COUT*CIN;
    h2 W00 = {(_Float16)w00,(_Float16)w00};
    h2 W01 = {(_Float16)w01,(_Float16)w01};
    h2 W10 = {(_Float16)w10,(_Float16)w10};
    h2 W11 = {(_Float16)w11,(_Float16)w11};
    // prologue: staging-0 corners (2 x dwordx4 per corner = 16 ch)
    U16x8 vc[4][2];
    #pragma unroll
    for(int c=0;c<4;c++){
      vc[c][0].q = *(const uint4*)(pc[c]);
      vc[c][1].q = *(const uint4*)(pc[c] + 8);
    }
    #pragma unroll 1
    for(int c0=0;c0<CIN;c0+=64){
      // prefetch next staging's corners (drained at the coming barrier, in flight now)
      U16x8 nc[4][2];
      if(c0+64 < CIN){
        #pragma unroll
        for(int c=0;c<4;c++){
          nc[c][0].q = *(const uint4*)(pc[c] + c0+64);
          nc[c][1].q = *(const uint4*)(pc[c] + c0+64 + 8);
        }
      }
      // current staging's B fragments (2 K-steps x NF)
      uint4 Bq[2][NF];
      #pragma unroll
      for(int ks=0;ks<2;ks++)
        #pragma unroll
        for(int ni=0;ni<NF;ni++)
          Bq[ks][ni] = *(const uint4*)(wk + (size_t)ni*16*CIN + c0 + ks*32);
      // packed-f16 lerp of current 16 channels
      U16x8 rr0, rr1;
      #pragma unroll
      for(int j=0;j<4;j++){
        rr0.v[j] = vc[0][0].v[j]*W00 + vc[1][0].v[j]*W01 + vc[2][0].v[j]*W10 + vc[3][0].v[j]*W11;
        rr1.v[j] = vc[0][1].v[j]*W00 + vc[1][1].v[j]*W01 + vc[2][1].v[j]*W10 + vc[3][1].v[j]*W11;
      }
      *(uint4*)&As[buf][pa*72 + ca]     = rr0.q;
      *(uint4*)&As[buf][pa*72 + ca + 8] = rr1.q;
      __syncthreads();
      UB afu[2][4];
      #pragma unroll
      for(int ks=0;ks<2;ks++)
        #pragma unroll
        for(int mi=0;mi<4;mi++)
          afu[ks][mi].q = *(const uint4*)&As[buf][(mi*16 + l15)*72 + ks*32 + quad*8];
      #pragma unroll
      for(int ks=0;ks<2;ks++)
        #pragma unroll
        for(int ni=0;ni<NF;ni++){
          UB bu; bu.q = Bq[ks][ni];
          #pragma unroll
          for(int mi=0;mi<4;mi++)
            acc[mi][ni] = __builtin_amdgcn_mfma_f32_16x16x32_f16(afu[ks][mi].f, bu.f, acc[mi][ni], 0,0,0);
        }
      if(c0+64 < CIN){
        #pragma unroll
        for(int c=0;c<4;c++){ vc[c][0]=nc[c][0]; vc[c][1]=nc[c][1]; }
      }
      buf ^= 1;
      // single barrier per staging: next write targets As[buf^1]; this buffer is
      // rewritten only after two more barriers -> WAR-safe.
    }
  }
  #pragma unroll
  for(int mi=0;mi<4;mi++){
    #pragma unroll
    for(int ni=0;ni<NF;ni++){
      int col = o0 + wave*NW + ni*16 + l15;
      if(MODE==1){
        float* out = (float*)outv + (size_t)blockIdx.z*PTOT*COUT;
        #pragma unroll
        for(int r=0;r<4;r++){
          int row = pos0 + mi*16 + quad*4 + r;
          out[(size_t)row*COUT + col] = acc[mi][ni][r];
        }
      } else {
        float bo = bias[col];
        _Float16* out = (_Float16*)outv;
        #pragma unroll
        for(int r=0;r<4;r++){
          int row = pos0 + mi*16 + quad*4 + r;
          out[(size_t)row*COUT + col] = (_Float16)(acc[mi][ni][r]+bo);
        }
      }
    }
  }
}

// ---- reduce 3 fp32 partial slabs -> f16 NHWC (+bias) ----
template<int COUT>
__global__ void k_redA(const float* __restrict__ part, const float* __restrict__ bias,
                       _Float16* __restrict__ out){
  int i4 = blockIdx.x*256 + threadIdx.x;
  constexpr int N4 = PTOT*COUT/4;
  if(i4 >= N4) return;
  const float4* p = (const float4*)part;
  float4 a = p[i4], b = p[i4 + N4], c = p[i4 + 2*N4];
  int col0 = (i4*4) & (COUT-1);
  float4 bi = *(const float4*)(bias + col0);
  UH4 r;
  r.h[0] = (_Float16)(a.x+b.x+c.x+bi.x);
  r.h[1] = (_Float16)(a.y+b.y+c.y+bi.y);
  r.h[2] = (_Float16)(a.z+b.z+c.z+bi.z);
  r.h[3] = (_Float16)(a.w+b.w+c.w+bi.w);
  *(uint2*)(out + (size_t)i4*4) = r.d;
}

// ---- reduce 3 fp32 partial slabs [P][256] -> fp32 NCHW (+bias), LDS transpose ----
__global__ void k_redT(const float* __restrict__ part, const float* __restrict__ bias,
                       float* __restrict__ out){
  __shared__ float t[32][33];
  constexpr int COUT = 256;
  constexpr size_t SL = (size_t)PTOT*COUT;
  int b = blockIdx.z;
  int p0 = blockIdx.x*32, c0 = blockIdx.y*32;
  int tx = threadIdx.x, ty = threadIdx.y; // 32x8
  #pragma unroll
  for(int i=0;i<32;i+=8){
    size_t idx = ((size_t)(b*HWP + p0+ty+i))*COUT + c0+tx;
    t[ty+i][tx] = part[idx] + part[idx+SL] + part[idx+2*SL];
  }
  __syncthreads();
  #pragma unroll
  for(int i=0;i<32;i+=8)
    out[((size_t)(b*COUT + c0+ty+i))*HWP + p0+tx] = t[tx][ty+i] + bias[c0+ty+i];
}

extern "C" void kernel_launch(void* const* d_in, const int* in_sizes, int n_in,
                              void* d_out, int out_size, void* d_ws, size_t ws_size,
                              hipStream_t stream){
  (void)in_sizes; (void)n_in; (void)out_size;
  const float* x   = (const float*)d_in[0];
  const float* ow1 = (const float*)d_in[1];
  const float* ob1 = (const float*)d_in[2];
  const float* w1  = (const float*)d_in[3];
  const float* b1  = (const float*)d_in[4];
  const float* ow2 = (const float*)d_in[5];
  const float* ob2 = (const float*)d_in[6];
  const float* w2  = (const float*)d_in[7];
  const float* b2  = (const float*)d_in[8];
  const float* ow3 = (const float*)d_in[9];
  const float* ob3 = (const float*)d_in[10];
  const float* w3  = (const float*)d_in[11];
  const float* b3  = (const float*)d_in[12];

  char* p = (char*)d_ws;
  auto carve = [&](size_t bytes)->char*{ char* r = p; p += (bytes + 255) & ~(size_t)255; return r; };
  _Float16* xh  = (_Float16*)carve((size_t)PTOT*64*2);
  _Float16* y1  = (_Float16*)carve((size_t)PTOT*64*2);
  _Float16* y2  = (_Float16*)carve((size_t)PTOT*512*2);
  _Float16* owT = (_Float16*)carve((size_t)9*32*512*2);
  _Float16* wT  = (_Float16*)carve((size_t)9*512*512*2);
  float*    om  = (float*)carve((size_t)3*PTOT*32*4);
  float*    pym = (float*)carve((size_t)PTOT*9*3*4);
  bool splitK = ws_size >= ((size_t)p - (size_t)d_ws) + (size_t)3*PTOT*256*4 + 4096;
  float* part = splitK ? (float*)carve((size_t)3*PTOT*256*4) : nullptr;

  k_nchw2nhwc<<<dim3(288,2,BBATCH), dim3(32,8), 0, stream>>>(x, xh);

  if(splitK){
    // ---- layer 1: 64 -> 64 (split-K gmain + redA) ----
    k_tow<64><<<(9*32*64+255)/256,256,0,stream>>>(ow1, owT);
    k_tw<64,64><<<(9*64*64+255)/256,256,0,stream>>>(w1, wT);
    k_goffs<64,3><<<dim3(PTOT/64,3),256,0,stream>>>(xh, owT, om);
    k_prep<3><<<(PTOT*9+255)/256,256,0,stream>>>(om, ob1, pym);
    k_gmain<64,64,64,1><<<dim3(PTOT/64,1,3),256,0,stream>>>(xh, pym, wT, b1, part);
    k_redA<64><<<(PTOT*64/4+255)/256,256,0,stream>>>(part, b1, y1);

    // ---- layer 2: 64 -> 512 (split goffs, direct gmain) ----
    k_tow<64><<<(9*32*64+255)/256,256,0,stream>>>(ow2, owT);
    k_tw<64,512><<<(9*512*64+255)/256,256,0,stream>>>(w2, wT);
    k_goffs<64,3><<<dim3(PTOT/64,3),256,0,stream>>>(y1, owT, om);
    k_prep<3><<<(PTOT*9+255)/256,256,0,stream>>>(om, ob2, pym);
    k_gmain<64,512,256,0><<<dim3(PTOT/64,2),256,0,stream>>>(y1, pym, wT, b2, y2);

    // ---- layer 3: 512 -> 256 (split-K gmain + redT) ----
    k_tow<512><<<(9*32*512+255)/256,256,0,stream>>>(ow3, owT);
    k_tw<512,256><<<(9*256*512+255)/256,256,0,stream>>>(w3, wT);
    k_goffs<512,3><<<dim3(PTOT/64,3),256,0,stream>>>(y2, owT, om);
    k_prep<3><<<(PTOT*9+255)/256,256,0,stream>>>(om, ob3, pym);
    k_gmain<512,256,256,1><<<dim3(PTOT/64,1,3),256,0,stream>>>(y2, pym, wT, b3, part);
    k_redT<<<dim3(288,8,4),dim3(32,8),0,stream>>>(part, b3, (float*)d_out);
  } else {
    // ---- fallback: non-split path ----
    k_tow<64><<<(9*32*64+255)/256,256,0,stream>>>(ow1, owT);
    k_tw<64,64><<<(9*64*64+255)/256,256,0,stream>>>(w1, wT);
    k_goffs<64,9><<<dim3(PTOT/64,1),256,0,stream>>>(xh, owT, om);
    k_prep<1><<<(PTOT*9+255)/256,256,0,stream>>>(om, ob1, pym);
    k_gmain<64,64,64,0><<<dim3(PTOT/64,1),256,0,stream>>>(xh, pym, wT, b1, y1);

    k_tow<64><<<(9*32*64+255)/256,256,0,stream>>>(ow2, owT);
    k_tw<64,512><<<(9*512*64+255)/256,256,0,stream>>>(w2, wT);
    k_goffs<64,9><<<dim3(PTOT/64,1),256,0,stream>>>(y1, owT, om);
    k_prep<1><<<(PTOT*9+255)/256,256,0,stream>>>(om, ob2, pym);
    k_gmain<64,512,256,0><<<dim3(PTOT/64,2),256,0,stream>>>(y1, pym, wT, b2, y2);

    k_tow<512><<<(9*32*512+255)/256,256,0,stream>>>(ow3, owT);
    k_tw<512,256><<<(9*256*512+255)/256,256,0,stream>>>(w3, wT);
    k_goffs<512,9><<<dim3(PTOT/64,1),256,0,stream>>>(y2, owT, om);
    k_prep<1><<<(PTOT*9+255)/256,256,0,stream>>>(om, ob3, pym);
    k_gmain<512,256,256,0><<<dim3(PTOT/64,1),256,0,stream>>>(y2, pym, wT, b3, y1);
    {
      struct L { static __global__ void tr(const _Float16* in, float* out){
        int i = blockIdx.x*256 + threadIdx.x;
        if(i >= PTOT*256) return;
        int c = i & 255, pnt = i >> 8;
        int bb = pnt / HWP, pr = pnt % HWP;
        out[((size_t)bb*256 + c)*HWP + pr] = (float)in[i];
      }};
      hipLaunchKernelGGL(L::tr, dim3((PTOT*256+255)/256), dim3(256), 0, stream,
                         (const _Float16*)y1, (float*)d_out);
    }
  }
}

// Round 9
// 407.348 us; speedup vs baseline: 1.2394x; 1.2394x over previous
//
#include <hip/hip_runtime.h>
#include <stdint.h>

// DCNv2 x3 for MI355X. fp32 I/O, fp16 internal + MFMA f16.
// R9 = R8 with B weights repacked into per-lane MFMA fragment order
//      (wTf[k][kg][ob][lane] uint4) -> B loads fully coalesced (8 seq lines
//      per instruction instead of 16 scattered). Everything else R8-identical.

#define HH 96
#define WW 96
#define BBATCH 4
#define HWP (HH*WW)        // 9216
#define PTOT (BBATCH*HWP)  // 36864

typedef _Float16 f16x8 __attribute__((ext_vector_type(8)));
typedef _Float16 h2    __attribute__((ext_vector_type(2)));
typedef float f32x4 __attribute__((ext_vector_type(4)));

union U16x8 { uint4 q; _Float16 h[8]; h2 v[4]; };
union UB    { uint4 q; f16x8 f; };
union UH4   { uint2 d; _Float16 h[4]; };

// ---- NCHW(f32, C=64) -> NHWC(f16) ----
__global__ void k_nchw2nhwc(const float* __restrict__ in, _Float16* __restrict__ out){
  __shared__ float t[32][33];
  int b = blockIdx.z;
  int p0 = blockIdx.x*32, c0 = blockIdx.y*32;
  int tx = threadIdx.x, ty = threadIdx.y; // 32x8
  #pragma unroll
  for(int i=0;i<32;i+=8)
    t[ty+i][tx] = in[((size_t)(b*64 + c0+ty+i))*HWP + p0+tx];
  __syncthreads();
  #pragma unroll
  for(int i=0;i<32;i+=8)
    out[((size_t)(b*HWP + p0+ty+i))*64 + c0+tx] = (_Float16)t[tx][ty+i];
}

// ---- ow [27][CIN][3][3] f32 -> owT [9][32][CIN] f16, rows 27..31 zero ----
template<int CIN>
__global__ void k_tow(const float* __restrict__ ow, _Float16* __restrict__ owT){
  int i = blockIdx.x*256 + threadIdx.x;
  if(i >= 9*32*CIN) return;
  int c = i % CIN; int j = (i/CIN)&31; int k = i/(CIN*32);
  owT[i] = (j<27) ? (_Float16)ow[((size_t)(j*CIN + c))*9 + k] : (_Float16)0.f;
}

// ---- w [COUT][CIN][3][3] f32 -> wTf fragment-packed f16:
//      element (k, g=c/32, ob=o/16, lane=((c%32)/8)*16 + o%16, j=c%8)
//      at ((((k*CIN/32+g)*COUT/16)+ob)*64 + lane)*8 + j ----
template<int CIN,int COUT>
__global__ void k_tw(const float* __restrict__ w, _Float16* __restrict__ wTf){
  int i = blockIdx.x*256 + threadIdx.x;
  if(i >= 9*COUT*CIN) return;
  int c = i % CIN; int o = (i/CIN)%COUT; int k = i/(CIN*COUT);
  int g = c>>5, quad = (c>>3)&3, j = c&7;
  int ob = o>>4, l15 = o&15;
  size_t dst = ((((size_t)k*(CIN/32) + g)*(COUT/16) + ob)*64 + quad*16 + l15)*8 + j;
  wTf[dst] = (_Float16)w[((size_t)(o*CIN + c))*9 + k];
}

// ---- offset conv GEMM, NT taps per block (R6 verbatim) ----
template<int CIN,int NT>
__launch_bounds__(256,2)
__global__ void k_goffs(const _Float16* __restrict__ xin, const _Float16* __restrict__ owT,
                        float* __restrict__ om){
  __shared__ __align__(16) _Float16 As[64*40];
  __shared__ __align__(16) _Float16 Bs[32*40];
  int pos0 = blockIdx.x*64;
  int K0 = blockIdx.y*NT;
  float* omo = om + (size_t)blockIdx.y*PTOT*32;
  int t = threadIdx.x;
  int lane = t&63, wave = t>>6;
  int quad = lane>>4, l15 = lane&15;
  f32x4 acc[2] = {};
  int pa = t>>2, ca = (t&3)*8;
  int P = pos0 + pa;
  int b = P/HWP, rem = P%HWP;
  int y = rem/WW, x = rem%WW;
  #pragma unroll 1
  for(int k=K0;k<K0+NT;k++){
    int iy = y + k/3 - 1, ix = x + k%3 - 1;
    bool valid = (iy>=0)&&(iy<HH)&&(ix>=0)&&(ix<WW);
    const _Float16* src = xin + (((size_t)b*HWP + iy*WW + ix)*CIN) + ca;
    #pragma unroll 1
    for(int c0=0;c0<CIN;c0+=32){
      uint4 av = make_uint4(0,0,0,0);
      if(valid) av = *(const uint4*)(src + c0);
      *(uint4*)&As[pa*40 + ca] = av;
      if(t < 128){
        int j = t>>2;
        *(uint4*)&Bs[j*40 + ca] = *(const uint4*)(owT + ((size_t)k*32 + j)*CIN + c0 + ca);
      }
      __syncthreads();
      UB afu; afu.q = *(const uint4*)&As[(wave*16 + l15)*40 + quad*8];
      #pragma unroll
      for(int ni=0;ni<2;ni++){
        UB bu; bu.q = *(const uint4*)&Bs[(ni*16 + l15)*40 + quad*8];
        acc[ni] = __builtin_amdgcn_mfma_f32_16x16x32_f16(afu.f, bu.f, acc[ni], 0,0,0);
      }
      __syncthreads();
    }
  }
  #pragma unroll
  for(int ni=0;ni<2;ni++)
    #pragma unroll
    for(int r=0;r<4;r++){
      int row = wave*16 + quad*4 + r;
      omo[(size_t)(pos0+row)*32 + ni*16 + l15] = acc[ni][r];
    }
}

// ---- per-(p,k) sampling params; sums NS om slabs (R6 verbatim) ----
template<int NS>
__global__ void k_prep(const float* __restrict__ om, const float* __restrict__ ob,
                       float* __restrict__ pym){
  int i = blockIdx.x*256 + threadIdx.x;
  if(i >= PTOT*9) return;
  int k = i%9, p = i/9;
  int rem = p%HWP;
  int y = rem/WW, x = rem%WW;
  float oy=0.f, ox=0.f, mm=0.f;
  #pragma unroll
  for(int s=0;s<NS;s++){
    const float* o = om + (size_t)s*PTOT*32 + (size_t)p*32;
    oy += o[2*k]; ox += o[2*k+1]; mm += o[18+k];
  }
  oy += ob[2*k]; ox += ob[2*k+1]; mm += ob[18+k];
  float m = 1.f/(1.f + expf(-mm));
  pym[(size_t)i*3+0] = (float)(y + k/3 - 1) + oy;
  pym[(size_t)i*3+1] = (float)(x + k%3 - 1) + ox;
  pym[(size_t)i*3+2] = m;
}

// ---- main DCN GEMM, R9: BK=64 staging, dbuf As, 1 barrier/staging,
//      fragment-packed B (coalesced per-lane loads).
//      MODE 0: 9 taps, f16 NHWC out (+bias).
//      MODE 1: 3 taps (blockIdx.z), fp32 partial out (no bias).
template<int CIN,int COUT,int BN,int MODE>
__launch_bounds__(256,2)
__global__ void k_gmain(const _Float16* __restrict__ xin, const float* __restrict__ pym,
                        const _Float16* __restrict__ wTf, const float* __restrict__ bias,
                        void* __restrict__ outv){
  constexpr int NW = BN/4;      // per-wave N width
  constexpr int NF = NW/16;     // n-frags per wave
  constexpr int KG = CIN/32;    // K-groups
  constexpr int OB = COUT/16;   // o-blocks
  __shared__ __align__(16) _Float16 As[2][64*72];   // 64 pos x 64ch, stride 72
  int bx = blockIdx.x;
  int lin = (bx>>3) + (bx&7)*(gridDim.x>>3);   // bijective: gridDim.x % 8 == 0
  int pos0 = lin*64;
  int o0 = blockIdx.y*BN;
  int K0 = (MODE==1) ? blockIdx.z*3 : 0;
  constexpr int KN = (MODE==1) ? 3 : 9;
  int t = threadIdx.x;
  int lane = t&63, wave = t>>6;
  int quad = lane>>4, l15 = lane&15;
  f32x4 acc[4][NF] = {};
  int pa = t>>2, ca = (t&3)*16;   // 16 channels per thread
  int P = pos0 + pa;
  int b = P/HWP;
  const _Float16* base = xin + (size_t)b*HWP*CIN + ca;
  const uint4* wf = (const uint4*)wTf;
  int obBase = (o0>>4) + wave*NF;
  int buf = 0;
  #pragma unroll 1
  for(int k=K0;k<K0+KN;k++){
    const float* pp = pym + ((size_t)P*9 + k)*3;
    float py = pp[0], px = pp[1], mk = pp[2];
    float y0f = floorf(py), x0f = floorf(px);
    float wy = py - y0f, wx = px - x0f;
    int iy0 = (int)y0f, ix0 = (int)x0f;
    int iy1 = iy0+1, ix1 = ix0+1;
    bool vy0 = (iy0>=0)&&(iy0<HH), vy1 = (iy1>=0)&&(iy1<HH);
    bool vx0 = (ix0>=0)&&(ix0<WW), vx1 = (ix1>=0)&&(ix1<WW);
    float w00 = (vy0&&vx0) ? (1.f-wy)*(1.f-wx)*mk : 0.f;
    float w01 = (vy0&&vx1) ? (1.f-wy)*wx*mk      : 0.f;
    float w10 = (vy1&&vx0) ? wy*(1.f-wx)*mk      : 0.f;
    float w11 = (vy1&&vx1) ? wy*wx*mk            : 0.f;
    int cy0 = min(max(iy0,0),HH-1), cy1 = min(max(iy1,0),HH-1);
    int cx0 = min(max(ix0,0),WW-1), cx1 = min(max(ix1,0),WW-1);
    const _Float16* pc[4];
    pc[0] = base + ((size_t)(cy0*WW+cx0))*CIN;
    pc[1] = base + ((size_t)(cy0*WW+cx1))*CIN;
    pc[2] = base + ((size_t)(cy1*WW+cx0))*CIN;
    pc[3] = base + ((size_t)(cy1*WW+cx1))*CIN;
    const uint4* wk = wf + (size_t)k*KG*OB*64 + lane;
    h2 W00 = {(_Float16)w00,(_Float16)w00};
    h2 W01 = {(_Float16)w01,(_Float16)w01};
    h2 W10 = {(_Float16)w10,(_Float16)w10};
    h2 W11 = {(_Float16)w11,(_Float16)w11};
    // prologue: staging-0 corners (2 x dwordx4 per corner = 16 ch)
    U16x8 vc[4][2];
    #pragma unroll
    for(int c=0;c<4;c++){
      vc[c][0].q = *(const uint4*)(pc[c]);
      vc[c][1].q = *(const uint4*)(pc[c] + 8);
    }
    #pragma unroll 1
    for(int c0=0;c0<CIN;c0+=64){
      // prefetch next staging's corners (in flight across the barrier)
      U16x8 nc[4][2];
      if(c0+64 < CIN){
        #pragma unroll
        for(int c=0;c<4;c++){
          nc[c][0].q = *(const uint4*)(pc[c] + c0+64);
          nc[c][1].q = *(const uint4*)(pc[c] + c0+64 + 8);
        }
      }
      // current staging's B fragments (2 K-steps x NF), fragment-packed: coalesced
      int g0 = c0>>5;
      uint4 Bq[2][NF];
      #pragma unroll
      for(int ks=0;ks<2;ks++)
        #pragma unroll
        for(int ni=0;ni<NF;ni++)
          Bq[ks][ni] = wk[ (size_t)(g0+ks)*OB*64 + (size_t)(obBase+ni)*64 ];
      // packed-f16 lerp of current 16 channels
      U16x8 rr0, rr1;
      #pragma unroll
      for(int j=0;j<4;j++){
        rr0.v[j] = vc[0][0].v[j]*W00 + vc[1][0].v[j]*W01 + vc[2][0].v[j]*W10 + vc[3][0].v[j]*W11;
        rr1.v[j] = vc[0][1].v[j]*W00 + vc[1][1].v[j]*W01 + vc[2][1].v[j]*W10 + vc[3][1].v[j]*W11;
      }
      *(uint4*)&As[buf][pa*72 + ca]     = rr0.q;
      *(uint4*)&As[buf][pa*72 + ca + 8] = rr1.q;
      __syncthreads();
      UB afu[2][4];
      #pragma unroll
      for(int ks=0;ks<2;ks++)
        #pragma unroll
        for(int mi=0;mi<4;mi++)
          afu[ks][mi].q = *(const uint4*)&As[buf][(mi*16 + l15)*72 + ks*32 + quad*8];
      #pragma unroll
      for(int ks=0;ks<2;ks++)
        #pragma unroll
        for(int ni=0;ni<NF;ni++){
          UB bu; bu.q = Bq[ks][ni];
          #pragma unroll
          for(int mi=0;mi<4;mi++)
            acc[mi][ni] = __builtin_amdgcn_mfma_f32_16x16x32_f16(afu[ks][mi].f, bu.f, acc[mi][ni], 0,0,0);
        }
      if(c0+64 < CIN){
        #pragma unroll
        for(int c=0;c<4;c++){ vc[c][0]=nc[c][0]; vc[c][1]=nc[c][1]; }
      }
      buf ^= 1;
      // single barrier per staging: next write targets As[buf^1]; this buffer is
      // rewritten only after two more barriers -> WAR-safe.
    }
  }
  #pragma unroll
  for(int mi=0;mi<4;mi++){
    #pragma unroll
    for(int ni=0;ni<NF;ni++){
      int col = o0 + wave*NW + ni*16 + l15;
      if(MODE==1){
        float* out = (float*)outv + (size_t)blockIdx.z*PTOT*COUT;
        #pragma unroll
        for(int r=0;r<4;r++){
          int row = pos0 + mi*16 + quad*4 + r;
          out[(size_t)row*COUT + col] = acc[mi][ni][r];
        }
      } else {
        float bo = bias[col];
        _Float16* out = (_Float16*)outv;
        #pragma unroll
        for(int r=0;r<4;r++){
          int row = pos0 + mi*16 + quad*4 + r;
          out[(size_t)row*COUT + col] = (_Float16)(acc[mi][ni][r]+bo);
        }
      }
    }
  }
}

// ---- reduce 3 fp32 partial slabs -> f16 NHWC (+bias) ----
template<int COUT>
__global__ void k_redA(const float* __restrict__ part, const float* __restrict__ bias,
                       _Float16* __restrict__ out){
  int i4 = blockIdx.x*256 + threadIdx.x;
  constexpr int N4 = PTOT*COUT/4;
  if(i4 >= N4) return;
  const float4* p = (const float4*)part;
  float4 a = p[i4], b = p[i4 + N4], c = p[i4 + 2*N4];
  int col0 = (i4*4) & (COUT-1);
  float4 bi = *(const float4*)(bias + col0);
  UH4 r;
  r.h[0] = (_Float16)(a.x+b.x+c.x+bi.x);
  r.h[1] = (_Float16)(a.y+b.y+c.y+bi.y);
  r.h[2] = (_Float16)(a.z+b.z+c.z+bi.z);
  r.h[3] = (_Float16)(a.w+b.w+c.w+bi.w);
  *(uint2*)(out + (size_t)i4*4) = r.d;
}

// ---- reduce 3 fp32 partial slabs [P][256] -> fp32 NCHW (+bias), LDS transpose ----
__global__ void k_redT(const float* __restrict__ part, const float* __restrict__ bias,
                       float* __restrict__ out){
  __shared__ float t[32][33];
  constexpr int COUT = 256;
  constexpr size_t SL = (size_t)PTOT*COUT;
  int b = blockIdx.z;
  int p0 = blockIdx.x*32, c0 = blockIdx.y*32;
  int tx = threadIdx.x, ty = threadIdx.y; // 32x8
  #pragma unroll
  for(int i=0;i<32;i+=8){
    size_t idx = ((size_t)(b*HWP + p0+ty+i))*COUT + c0+tx;
    t[ty+i][tx] = part[idx] + part[idx+SL] + part[idx+2*SL];
  }
  __syncthreads();
  #pragma unroll
  for(int i=0;i<32;i+=8)
    out[((size_t)(b*COUT + c0+ty+i))*HWP + p0+tx] = t[tx][ty+i] + bias[c0+ty+i];
}

extern "C" void kernel_launch(void* const* d_in, const int* in_sizes, int n_in,
                              void* d_out, int out_size, void* d_ws, size_t ws_size,
                              hipStream_t stream){
  (void)in_sizes; (void)n_in; (void)out_size;
  const float* x   = (const float*)d_in[0];
  const float* ow1 = (const float*)d_in[1];
  const float* ob1 = (const float*)d_in[2];
  const float* w1  = (const float*)d_in[3];
  const float* b1  = (const float*)d_in[4];
  const float* ow2 = (const float*)d_in[5];
  const float* ob2 = (const float*)d_in[6];
  const float* w2  = (const float*)d_in[7];
  const float* b2  = (const float*)d_in[8];
  const float* ow3 = (const float*)d_in[9];
  const float* ob3 = (const float*)d_in[10];
  const float* w3  = (const float*)d_in[11];
  const float* b3  = (const float*)d_in[12];

  char* p = (char*)d_ws;
  auto carve = [&](size_t bytes)->char*{ char* r = p; p += (bytes + 255) & ~(size_t)255; return r; };
  _Float16* xh  = (_Float16*)carve((size_t)PTOT*64*2);
  _Float16* y1  = (_Float16*)carve((size_t)PTOT*64*2);
  _Float16* y2  = (_Float16*)carve((size_t)PTOT*512*2);
  _Float16* owT = (_Float16*)carve((size_t)9*32*512*2);
  _Float16* wT  = (_Float16*)carve((size_t)9*512*512*2);
  float*    om  = (float*)carve((size_t)3*PTOT*32*4);
  float*    pym = (float*)carve((size_t)PTOT*9*3*4);
  bool splitK = ws_size >= ((size_t)p - (size_t)d_ws) + (size_t)3*PTOT*256*4 + 4096;
  float* part = splitK ? (float*)carve((size_t)3*PTOT*256*4) : nullptr;

  k_nchw2nhwc<<<dim3(288,2,BBATCH), dim3(32,8), 0, stream>>>(x, xh);

  if(splitK){
    // ---- layer 1: 64 -> 64 (split-K gmain + redA) ----
    k_tow<64><<<(9*32*64+255)/256,256,0,stream>>>(ow1, owT);
    k_tw<64,64><<<(9*64*64+255)/256,256,0,stream>>>(w1, wT);
    k_goffs<64,3><<<dim3(PTOT/64,3),256,0,stream>>>(xh, owT, om);
    k_prep<3><<<(PTOT*9+255)/256,256,0,stream>>>(om, ob1, pym);
    k_gmain<64,64,64,1><<<dim3(PTOT/64,1,3),256,0,stream>>>(xh, pym, wT, b1, part);
    k_redA<64><<<(PTOT*64/4+255)/256,256,0,stream>>>(part, b1, y1);

    // ---- layer 2: 64 -> 512 (split goffs, direct gmain) ----
    k_tow<64><<<(9*32*64+255)/256,256,0,stream>>>(ow2, owT);
    k_tw<64,512><<<(9*512*64+255)/256,256,0,stream>>>(w2, wT);
    k_goffs<64,3><<<dim3(PTOT/64,3),256,0,stream>>>(y1, owT, om);
    k_prep<3><<<(PTOT*9+255)/256,256,0,stream>>>(om, ob2, pym);
    k_gmain<64,512,256,0><<<dim3(PTOT/64,2),256,0,stream>>>(y1, pym, wT, b2, y2);

    // ---- layer 3: 512 -> 256 (split-K gmain + redT) ----
    k_tow<512><<<(9*32*512+255)/256,256,0,stream>>>(ow3, owT);
    k_tw<512,256><<<(9*256*512+255)/256,256,0,stream>>>(w3, wT);
    k_goffs<512,3><<<dim3(PTOT/64,3),256,0,stream>>>(y2, owT, om);
    k_prep<3><<<(PTOT*9+255)/256,256,0,stream>>>(om, ob3, pym);
    k_gmain<512,256,256,1><<<dim3(PTOT/64,1,3),256,0,stream>>>(y2, pym, wT, b3, part);
    k_redT<<<dim3(288,8,4),dim3(32,8),0,stream>>>(part, b3, (float*)d_out);
  } else {
    // ---- fallback: non-split path ----
    k_tow<64><<<(9*32*64+255)/256,256,0,stream>>>(ow1, owT);
    k_tw<64,64><<<(9*64*64+255)/256,256,0,stream>>>(w1, wT);
    k_goffs<64,9><<<dim3(PTOT/64,1),256,0,stream>>>(xh, owT, om);
    k_prep<1><<<(PTOT*9+255)/256,256,0,stream>>>(om, ob1, pym);
    k_gmain<64,64,64,0><<<dim3(PTOT/64,1),256,0,stream>>>(xh, pym, wT, b1, y1);

    k_tow<64><<<(9*32*64+255)/256,256,0,stream>>>(ow2, owT);
    k_tw<64,512><<<(9*512*64+255)/256,256,0,stream>>>(w2, wT);
    k_goffs<64,9><<<dim3(PTOT/64,1),256,0,stream>>>(y1, owT, om);
    k_prep<1><<<(PTOT*9+255)/256,256,0,stream>>>(om, ob2, pym);
    k_gmain<64,512,256,0><<<dim3(PTOT/64,2),256,0,stream>>>(y1, pym, wT, b2, y2);

    k_tow<512><<<(9*32*512+255)/256,256,0,stream>>>(ow3, owT);
    k_tw<512,256><<<(9*256*512+255)/256,256,0,stream>>>(w3, wT);
    k_goffs<512,9><<<dim3(PTOT/64,1),256,0,stream>>>(y2, owT, om);
    k_prep<1><<<(PTOT*9+255)/256,256,0,stream>>>(om, ob3, pym);
    k_gmain<512,256,256,0><<<dim3(PTOT/64,1),256,0,stream>>>(y2, pym, wT, b3, y1);
    {
      struct L { static __global__ void tr(const _Float16* in, float* out){
        int i = blockIdx.x*256 + threadIdx.x;
        if(i >= PTOT*256) return;
        int c = i & 255, pnt = i >> 8;
        int bb = pnt / HWP, pr = pnt % HWP;
        out[((size_t)bb*256 + c)*HWP + pr] = (float)in[i];
      }};
      hipLaunchKernelGGL(L::tr, dim3((PTOT*256+255)/256), dim3(256), 0, stream,
                         (const _Float16*)y1, (float*)d_out);
    }
  }
}